// Round 17
// baseline (293.891 us; speedup 1.0000x reference)
//
#include <hip/hip_runtime.h>

typedef unsigned short u16;
typedef __attribute__((ext_vector_type(8))) short bh8;   // 8 bf16
typedef __attribute__((ext_vector_type(4))) float f4;

__device__ inline u16 f2bf(float f) {
  union { float f; unsigned u; } v; v.f = f;
  unsigned r = v.u + 0x7FFFu + ((v.u >> 16) & 1u);   // RNE
  return (u16)(r >> 16);
}

// ---------------- conversion: x (fp32) -> bf16 ----------------
__global__ __launch_bounds__(256) void convx_kernel(const float* __restrict__ x,
                                                    u16* __restrict__ xb, int n8) {
  int i = blockIdx.x * 256 + threadIdx.x;
  if (i >= n8) return;
  const float4* xf = (const float4*)x;
  float4 a = xf[2 * i], b = xf[2 * i + 1];
  alignas(16) u16 o[8] = { f2bf(a.x), f2bf(a.y), f2bf(a.z), f2bf(a.w),
                           f2bf(b.x), f2bf(b.y), f2bf(b.z), f2bf(b.w) };
  *(int4*)(xb + (size_t)i * 8) = *(const int4*)o;
}

// ------------- transpose + convert: W[K][N] fp32 -> Wt[N][K] bf16 (x scale) -------------
__global__ __launch_bounds__(256) void tconv_kernel(const float* __restrict__ W,
                                                    u16* __restrict__ Wt,
                                                    int K, int N, float scale) {
  __shared__ float tile[32][33];
  int nb = blockIdx.x * 32, kb = blockIdx.y * 32;
  int tx = threadIdx.x, ty = threadIdx.y;
  for (int i = ty; i < 32; i += 8)
    tile[i][tx] = W[(size_t)(kb + i) * N + nb + tx];
  __syncthreads();
  for (int i = ty; i < 32; i += 8)
    Wt[(size_t)(nb + i) * K + kb + tx] = f2bf(tile[tx][i] * scale);
}

// ------------- V transpose: QKV V-cols [b][2048][512] -> VT[b][512][2048] bf16 -------------
__global__ __launch_bounds__(256) void vtrans_kernel(const u16* __restrict__ QKV,
                                                     u16* __restrict__ VT) {
  __shared__ u16 tile[32][33];
  int nb = blockIdx.x * 32, cb = blockIdx.y * 32, b = blockIdx.z;
  int tx = threadIdx.x, ty = threadIdx.y;
  for (int i = ty; i < 32; i += 8)
    tile[i][tx] = QKV[(size_t)(b * 2048 + nb + i) * 3072 + 2560 + cb + tx];
  __syncthreads();
  for (int i = ty; i < 32; i += 8)
    VT[((size_t)b * 512 + cb + i) * 2048 + nb + tx] = tile[tx][i];
}

// ---------------- async global->LDS 16B ----------------
__device__ inline void gload16(const u16* g, u16* l) {
  __builtin_amdgcn_global_load_lds(
      (const __attribute__((address_space(1))) unsigned int*)g,
      (__attribute__((address_space(3))) unsigned int*)l, 16, 0, 0);
}

__device__ inline unsigned cvtpk_bf16(float lo, float hi) {
  unsigned r;
  asm("v_cvt_pk_bf16_f32 %0, %1, %2" : "=v"(r) : "v"(lo), "v"(hi));
  return r;
}

// softmax scale folded into wq at tconv: 0.125 * log2(e)
#define QK_SC2 0.18033688011112042f

// ---------------- GEMM: C[M][N] = A[M][K] * Bt[N][K]^T  (BK=64, verified r16) ----------------
template <typename OutT>
__global__ __launch_bounds__(256) void gemm_bt(const u16* __restrict__ A,
                                               const u16* __restrict__ Bt,
                                               OutT* __restrict__ C,
                                               int M, int N, int K) {
  __shared__ u16 As[128 * 64];   // 16 KB
  __shared__ u16 Bs[128 * 64];   // 16 KB
  const int t = threadIdx.x;
  const int lane = t & 63, w = t >> 6;
  const int wr = w >> 1, wc = w & 1;
  const int fr = lane & 15, fq = lane >> 4;
  const int rowBase = blockIdx.y * 128, colBase = blockIdx.x * 128;
  f4 acc[4][4] = {};
  const u16* Ag = A + (size_t)rowBase * K;
  const u16* Bg = Bt + (size_t)colBase * K;
  for (int kt = 0; kt < K; kt += 64) {
    __syncthreads();
#pragma unroll
    for (int i = 0; i < 4; i++) {
      int c = t + i * 256;
      int row = c >> 3, sl = (c ^ row) & 7;
      gload16(Ag + (size_t)row * K + kt + sl * 8, As + c * 8);
    }
#pragma unroll
    for (int i = 0; i < 4; i++) {
      int c = t + i * 256;
      int row = c >> 3, sl = (c ^ row) & 7;
      gload16(Bg + (size_t)row * K + kt + sl * 8, Bs + c * 8);
    }
    __syncthreads();
#pragma unroll
    for (int kk = 0; kk < 2; kk++) {
      bh8 a[4], b[4];
#pragma unroll
      for (int m = 0; m < 4; m++) {
        int row = wr * 64 + m * 16 + fr;
        int sl = (kk * 4 + fq) ^ (row & 7);
        a[m] = *(const bh8*)(As + row * 64 + sl * 8);
      }
#pragma unroll
      for (int n = 0; n < 4; n++) {
        int row = wc * 64 + n * 16 + fr;
        int sl = (kk * 4 + fq) ^ (row & 7);
        b[n] = *(const bh8*)(Bs + row * 64 + sl * 8);
      }
#pragma unroll
      for (int m = 0; m < 4; m++)
#pragma unroll
        for (int n = 0; n < 4; n++)
          acc[m][n] = __builtin_amdgcn_mfma_f32_16x16x32_bf16(a[m], b[n], acc[m][n], 0, 0, 0);
    }
  }
#pragma unroll
  for (int m = 0; m < 4; m++)
#pragma unroll
    for (int n = 0; n < 4; n++)
#pragma unroll
      for (int r = 0; r < 4; r++) {
        int row = rowBase + wr * 64 + m * 16 + fq * 4 + r;
        int col = colBase + wc * 64 + n * 16 + fr;
        float v = acc[m][n][r];
        if constexpr (sizeof(OutT) == 2)
          ((u16*)C)[(size_t)row * N + col] = f2bf(v);
        else
          ((float*)C)[(size_t)row * N + col] = v;
      }
}

// ---------------- fused flash attention (GQA, no mask) ----------------
// Round-13/16 verified math core with 4 SUB-TILES PER WAVE (64 q-rows/wave,
// 256 q-rows/block, 512 blocks). Rationale (r14 lesson): per-iter FIXED costs
// (staging, drain+barrier, K/V LDS re-reads) dominate; 4 subs amortize them
// over 2x FLOPs. c-outer QK (K frags read once, shared by all subs), per-sub
// exp/pack with the r13 WAR fence, hc-outer PV (V frags read once, shared).
// Staging/swizzles/fence byte-identical to r16. LDS 40960 B; 2 blocks/CU.
// QKV: [4096][3072] bf16; VT: [b][512][2048] bf16; AO: [4096][2048] bf16.
__global__ __launch_bounds__(256) void attn_kernel(const u16* __restrict__ QKV,
                                                   const u16* __restrict__ VT,
                                                   u16* __restrict__ AO) {
  __shared__ u16 Ks[2][4096];       // 16384 B: [64 keys][64 hd], swizzled 16B slots
  __shared__ u16 Vs[2][4096];       // 16384 B: [64 hd][64 keys], swizzled 16B slots
  __shared__ u16 Plds[4][16][64];   //  8192 B: [wave][q][key], XOR-swizzled, per-sub reuse
  const int t = threadIdx.x, lane = t & 63, w = t >> 6;
  const int fr = lane & 15, fq = lane >> 4;
  const int blk = blockIdx.x;
  const int qt = blk & 7;              // 8 q-tiles of 256 rows
  const int h  = (blk >> 3) & 31;
  const int b  = blk >> 8;
  const int kvh = h >> 2;
  const size_t rowb = (size_t)b * 2048;
  const u16* Qb  = QKV + rowb * 3072 + h * 64;
  const u16* Kb  = QKV + rowb * 3072 + 2048 + kvh * 64;
  const u16* VTb = VT + ((size_t)b * 512 + kvh * 64) * 2048;   // VT[hd][n]
  const int qrow0 = qt * 256 + w * 64;

  // Q fragments (pre-scaled by QK_SC2 via the wq tconv)
  bh8 qf[4][2];
#pragma unroll
  for (int sub = 0; sub < 4; sub++)
#pragma unroll
    for (int kk = 0; kk < 2; kk++)
      qf[sub][kk] = *(const bh8*)(Qb + (size_t)(qrow0 + sub * 16 + fr) * 3072 + kk * 32 + fq * 8);

  // all-ones bf16 B-fragment for the rowsum MFMA
  const bh8 ones8 = {0x3F80, 0x3F80, 0x3F80, 0x3F80, 0x3F80, 0x3F80, 0x3F80, 0x3F80};

  // Staging (byte-identical to r16): chunk c covers tile row c>>3, 16B slot c&7;
  // LDS dest linear; global source uses inverse swizzle slot' = (c ^ (c>>3)) & 7.
  const int c0 = t, c1 = t + 256;
  const int r0 = c0 >> 3, s0 = (c0 ^ r0) & 7;
  const int r1 = c1 >> 3, s1 = (c1 ^ r1) & 7;
  const u16* ksrc0 = Kb  + (size_t)r0 * 3072 + s0 * 8;
  const u16* ksrc1 = Kb  + (size_t)r1 * 3072 + s1 * 8;
  const u16* vsrc0 = VTb + (size_t)r0 * 2048 + s0 * 8;
  const u16* vsrc1 = VTb + (size_t)r1 * 2048 + s1 * 8;

#define STAGE(buf, kb_) do {                                              \
    gload16(ksrc0 + (size_t)(kb_) * 64 * 3072, &Ks[buf][c0 * 8]);         \
    gload16(ksrc1 + (size_t)(kb_) * 64 * 3072, &Ks[buf][c1 * 8]);         \
    gload16(vsrc0 + (size_t)(kb_) * 64,        &Vs[buf][c0 * 8]);         \
    gload16(vsrc1 + (size_t)(kb_) * 64,        &Vs[buf][c1 * 8]);         \
  } while (0)

  STAGE(0, 0);
  asm volatile("s_waitcnt vmcnt(0)");
  __syncthreads();

  // swizzled read offset: tile row fr, global slot fq -> LDS slot fq^(fr&7)
  const unsigned rdOf = (unsigned)(fr * 128) + ((unsigned)(fq ^ (fr & 7)) << 4);
  // Plds row base (row = q = fr) and per-lane XOR swizzle
  char* Prow = (char*)&Plds[w][fr][0];
  const unsigned pswz = (unsigned)((fr & 7) << 4);

  f4 oacc[4][4] = {};
  f4 lacc[4] = {};

  for (int kb = 0; kb < 32; kb++) {
    const int cur = kb & 1;
    if (kb + 1 < 32) STAGE(cur ^ 1, kb + 1);

    const char* Kt  = (const char*)&Ks[cur][0];
    const char* Vtl = (const char*)&Vs[cur][0];

    // --- S^T = K Q^T (swapped operands), c-outer: K frags read ONCE, shared
    //     by all 4 subs. lane holds S[q=fr][key=c*16+fq*4+r], pre-scaled. ---
    f4 sf[4][4];
#pragma unroll
    for (int c = 0; c < 4; c++) {
      bh8 k0 = *(const bh8*)(Kt + c * 2048 + rdOf);
      bh8 k1 = *(const bh8*)(Kt + c * 2048 + (rdOf ^ 64));
#pragma unroll
      for (int sub = 0; sub < 4; sub++) {
        f4 s = {};
        s = __builtin_amdgcn_mfma_f32_16x16x32_bf16(k0, qf[sub][0], s, 0, 0, 0);
        s = __builtin_amdgcn_mfma_f32_16x16x32_bf16(k1, qf[sub][1], s, 0, 0, 0);
        sf[sub][c] = s;
      }
    }

    // --- P = exp2(S): per sub, pack 4 keys -> 1 b64 swizzled write, read the
    //     A-frags back; Plds reused across subs with the r13 WAR fence. ---
    bh8 pa[4][2];
#pragma unroll
    for (int sub = 0; sub < 4; sub++) {
#pragma unroll
      for (int c = 0; c < 4; c++) {
        float p0 = exp2f(sf[sub][c][0]);
        float p1 = exp2f(sf[sub][c][1]);
        float p2 = exp2f(sf[sub][c][2]);
        float p3 = exp2f(sf[sub][c][3]);
        union { unsigned u[2]; unsigned long long ll; } pk;
        pk.u[0] = cvtpk_bf16(p0, p1);
        pk.u[1] = cvtpk_bf16(p2, p3);
        *(unsigned long long*)(Prow + (((unsigned)(c * 32 + fq * 8)) ^ pswz)) = pk.ll;
      }
      pa[sub][0] = *(const bh8*)(Prow + (((unsigned)(fq * 16)) ^ pswz));
      pa[sub][1] = *(const bh8*)(Prow + (((unsigned)(64 + fq * 16)) ^ pswz));
      asm volatile("s_waitcnt lgkmcnt(0)" ::: "memory");   // WAR fence: reads landed
    }

    // --- PV, hc-outer: V frags read ONCE, shared by all 4 subs ---
#pragma unroll
    for (int hc = 0; hc < 4; hc++) {
      bh8 v0 = *(const bh8*)(Vtl + hc * 2048 + rdOf);
      bh8 v1 = *(const bh8*)(Vtl + hc * 2048 + (rdOf ^ 64));
#pragma unroll
      for (int sub = 0; sub < 4; sub++) {
        oacc[sub][hc] = __builtin_amdgcn_mfma_f32_16x16x32_bf16(pa[sub][0], v0, oacc[sub][hc], 0, 0, 0);
        oacc[sub][hc] = __builtin_amdgcn_mfma_f32_16x16x32_bf16(pa[sub][1], v1, oacc[sub][hc], 0, 0, 0);
      }
    }
#pragma unroll
    for (int sub = 0; sub < 4; sub++) {
      lacc[sub] = __builtin_amdgcn_mfma_f32_16x16x32_bf16(pa[sub][0], ones8, lacc[sub], 0, 0, 0);
      lacc[sub] = __builtin_amdgcn_mfma_f32_16x16x32_bf16(pa[sub][1], ones8, lacc[sub], 0, 0, 0);
    }

    asm volatile("s_waitcnt vmcnt(0)");
    __syncthreads();
  }
#undef STAGE

  // --- epilogue: O / l ---
#pragma unroll
  for (int sub = 0; sub < 4; sub++)
#pragma unroll
    for (int r = 0; r < 4; r++) {
      float inv = 1.f / lacc[sub][r];
#pragma unroll
      for (int hc = 0; hc < 4; hc++) {
        float v = oacc[sub][hc][r] * inv;
        AO[(rowb + qrow0 + sub * 16 + fq * 4 + r) * 2048 + h * 64 + hc * 16 + fr] = f2bf(v);
      }
    }
}

extern "C" void kernel_launch(void* const* d_in, const int* in_sizes, int n_in,
                              void* d_out, int out_size, void* d_ws, size_t ws_size,
                              hipStream_t stream) {
  const float* x  = (const float*)d_in[0];
  const float* wq = (const float*)d_in[1];
  const float* wk = (const float*)d_in[2];
  const float* wv = (const float*)d_in[3];
  const float* wo = (const float*)d_in[4];
  float* out = (float*)d_out;
  char* ws = (char*)d_ws;
  u16* xb    = (u16*)(ws);                               // [4096][2048] bf16, 16 MB
  u16* AO    = (u16*)(ws);                               // [4096][2048] bf16 (reuse, xb dead)
  u16* wqkvT = (u16*)(ws + 16777216);                    // [3072][2048] bf16, 12 MB
  u16* VT    = (u16*)(ws + 16777216);                    // [2][512][2048] bf16, 4 MB (reuse, wqkvT dead)
  u16* woT   = (u16*)(ws + 16777216 + 12582912);         // [2048][2048] bf16, 8 MB
  u16* QKV   = (u16*)(ws + 37748736);                    // [4096][3072] bf16, 24 MB

  convx_kernel<<<4096, 256, 0, stream>>>(x, xb, 1048576);
  dim3 tb(32, 8);
  tconv_kernel<<<dim3(64, 64), tb, 0, stream>>>(wq, wqkvT, 2048, 2048, QK_SC2);
  tconv_kernel<<<dim3(16, 64), tb, 0, stream>>>(wk, wqkvT + (size_t)2048 * 2048, 2048, 512, 1.0f);
  tconv_kernel<<<dim3(16, 64), tb, 0, stream>>>(wv, wqkvT + (size_t)2560 * 2048, 2048, 512, 1.0f);
  tconv_kernel<<<dim3(64, 64), tb, 0, stream>>>(wo, woT, 2048, 2048, 1.0f);

  gemm_bt<u16><<<dim3(24, 32), 256, 0, stream>>>(xb, wqkvT, QKV, 4096, 3072, 2048);
  vtrans_kernel<<<dim3(64, 16, 2), tb, 0, stream>>>(QKV, VT);   // wqkvT dead -> VT
  attn_kernel<<<512, 256, 0, stream>>>(QKV, VT, AO);
  gemm_bt<float><<<dim3(16, 32), 256, 0, stream>>>(AO, woT, out, 4096, 2048, 2048);
}

// Round 18
// 248.915 us; speedup vs baseline: 1.1807x; 1.1807x over previous
//
#include <hip/hip_runtime.h>

typedef unsigned short u16;
typedef __attribute__((ext_vector_type(8))) short bh8;   // 8 bf16
typedef __attribute__((ext_vector_type(4))) float f4;

__device__ inline u16 f2bf(float f) {
  union { float f; unsigned u; } v; v.f = f;
  unsigned r = v.u + 0x7FFFu + ((v.u >> 16) & 1u);   // RNE
  return (u16)(r >> 16);
}

// ---------------- conversion: x (fp32) -> bf16 ----------------
__global__ __launch_bounds__(256) void convx_kernel(const float* __restrict__ x,
                                                    u16* __restrict__ xb, int n8) {
  int i = blockIdx.x * 256 + threadIdx.x;
  if (i >= n8) return;
  const float4* xf = (const float4*)x;
  float4 a = xf[2 * i], b = xf[2 * i + 1];
  alignas(16) u16 o[8] = { f2bf(a.x), f2bf(a.y), f2bf(a.z), f2bf(a.w),
                           f2bf(b.x), f2bf(b.y), f2bf(b.z), f2bf(b.w) };
  *(int4*)(xb + (size_t)i * 8) = *(const int4*)o;
}

// softmax scale folded into wq at tconv: 0.125 * log2(e)
#define QK_SC2 0.18033688011112042f

// ------------- fused transpose+convert of all 4 weights (1 launch, was 4) -------------
// W[K=2048][N] fp32 -> Wt[N][2048] bf16 (x scale). Per-block uniform branch picks
// {W, Wt, N, scale}; inner code identical to the verified tconv.
// grid = dim3(160, 64): bx<64 wq | <80 wk | <96 wv | else wo.
__global__ __launch_bounds__(256) void tconv4_kernel(const float* __restrict__ wq,
                                                     const float* __restrict__ wk,
                                                     const float* __restrict__ wv,
                                                     const float* __restrict__ wo,
                                                     u16* __restrict__ wqkvT,
                                                     u16* __restrict__ woT) {
  const int bx = blockIdx.x, by = blockIdx.y;
  const float* W; u16* Wt; int N; float scale; int nbx;
  if (bx < 64)      { W = wq; Wt = wqkvT;                      N = 2048; scale = QK_SC2; nbx = bx; }
  else if (bx < 80) { W = wk; Wt = wqkvT + (size_t)2048 * 2048; N = 512; scale = 1.0f;  nbx = bx - 64; }
  else if (bx < 96) { W = wv; Wt = wqkvT + (size_t)2560 * 2048; N = 512; scale = 1.0f;  nbx = bx - 80; }
  else              { W = wo; Wt = woT;                        N = 2048; scale = 1.0f;  nbx = bx - 96; }
  __shared__ float tile[32][33];
  int nb = nbx * 32, kb = by * 32;
  int tx = threadIdx.x, ty = threadIdx.y;
  for (int i = ty; i < 32; i += 8)
    tile[i][tx] = W[(size_t)(kb + i) * N + nb + tx];
  __syncthreads();
  for (int i = ty; i < 32; i += 8)
    Wt[(size_t)(nb + i) * 2048 + kb + tx] = f2bf(tile[tx][i] * scale);
}

// ------------- V transpose: QKV V-cols [b][2048][512] -> VT[b][512][2048] bf16 -------------
__global__ __launch_bounds__(256) void vtrans_kernel(const u16* __restrict__ QKV,
                                                     u16* __restrict__ VT) {
  __shared__ u16 tile[32][33];
  int nb = blockIdx.x * 32, cb = blockIdx.y * 32, b = blockIdx.z;
  int tx = threadIdx.x, ty = threadIdx.y;
  for (int i = ty; i < 32; i += 8)
    tile[i][tx] = QKV[(size_t)(b * 2048 + nb + i) * 3072 + 2560 + cb + tx];
  __syncthreads();
  for (int i = ty; i < 32; i += 8)
    VT[((size_t)b * 512 + cb + i) * 2048 + nb + tx] = tile[tx][i];
}

// ---------------- async global->LDS 16B ----------------
__device__ inline void gload16(const u16* g, u16* l) {
  __builtin_amdgcn_global_load_lds(
      (const __attribute__((address_space(1))) unsigned int*)g,
      (__attribute__((address_space(3))) unsigned int*)l, 16, 0, 0);
}

__device__ inline unsigned cvtpk_bf16(float lo, float hi) {
  unsigned r;
  asm("v_cvt_pk_bf16_f32 %0, %1, %2" : "=v"(r) : "v"(lo), "v"(hi));
  return r;
}

// ---------------- GEMM: C[M][N] = A[M][K] * Bt[N][K]^T  (BK=64, verified r16) ----------------
template <typename OutT>
__global__ __launch_bounds__(256) void gemm_bt(const u16* __restrict__ A,
                                               const u16* __restrict__ Bt,
                                               OutT* __restrict__ C,
                                               int M, int N, int K) {
  __shared__ u16 As[128 * 64];   // 16 KB
  __shared__ u16 Bs[128 * 64];   // 16 KB
  const int t = threadIdx.x;
  const int lane = t & 63, w = t >> 6;
  const int wr = w >> 1, wc = w & 1;
  const int fr = lane & 15, fq = lane >> 4;
  const int rowBase = blockIdx.y * 128, colBase = blockIdx.x * 128;
  f4 acc[4][4] = {};
  const u16* Ag = A + (size_t)rowBase * K;
  const u16* Bg = Bt + (size_t)colBase * K;
  for (int kt = 0; kt < K; kt += 64) {
    __syncthreads();
#pragma unroll
    for (int i = 0; i < 4; i++) {
      int c = t + i * 256;
      int row = c >> 3, sl = (c ^ row) & 7;
      gload16(Ag + (size_t)row * K + kt + sl * 8, As + c * 8);
    }
#pragma unroll
    for (int i = 0; i < 4; i++) {
      int c = t + i * 256;
      int row = c >> 3, sl = (c ^ row) & 7;
      gload16(Bg + (size_t)row * K + kt + sl * 8, Bs + c * 8);
    }
    __syncthreads();
#pragma unroll
    for (int kk = 0; kk < 2; kk++) {
      bh8 a[4], b[4];
#pragma unroll
      for (int m = 0; m < 4; m++) {
        int row = wr * 64 + m * 16 + fr;
        int sl = (kk * 4 + fq) ^ (row & 7);
        a[m] = *(const bh8*)(As + row * 64 + sl * 8);
      }
#pragma unroll
      for (int n = 0; n < 4; n++) {
        int row = wc * 64 + n * 16 + fr;
        int sl = (kk * 4 + fq) ^ (row & 7);
        b[n] = *(const bh8*)(Bs + row * 64 + sl * 8);
      }
#pragma unroll
      for (int m = 0; m < 4; m++)
#pragma unroll
        for (int n = 0; n < 4; n++)
          acc[m][n] = __builtin_amdgcn_mfma_f32_16x16x32_bf16(a[m], b[n], acc[m][n], 0, 0, 0);
    }
  }
#pragma unroll
  for (int m = 0; m < 4; m++)
#pragma unroll
    for (int n = 0; n < 4; n++)
#pragma unroll
      for (int r = 0; r < 4; r++) {
        int row = rowBase + wr * 64 + m * 16 + fq * 4 + r;
        int col = colBase + wc * 64 + n * 16 + fr;
        float v = acc[m][n][r];
        if constexpr (sizeof(OutT) == 2)
          ((u16*)C)[(size_t)row * N + col] = f2bf(v);
        else
          ((float*)C)[(size_t)row * N + col] = v;
      }
}

// ---------------- fused flash attention (GQA, no mask) ----------------
// BYTE-IDENTICAL to the round-13/16 verified kernel -- the empirical optimum:
// r14 (smaller tile, more blocks) and r17 (bigger per-wave tile, fewer blocks)
// both regressed; swizzle/fexp2/single-buffer variants all failed correctness.
// V double-buffered, LDS 40960 B -> 4 blocks/CU, WAR fence after each sub's
// P reads, linear blockIdx, exp2f.
// QKV: [4096][3072] bf16; VT: [b][512][2048] bf16; AO: [4096][2048] bf16.
__global__ __launch_bounds__(256) void attn_kernel(const u16* __restrict__ QKV,
                                                   const u16* __restrict__ VT,
                                                   u16* __restrict__ AO) {
  __shared__ u16 Ks[2][4096];       // 16384 B: [64 keys][64 hd], swizzled 16B slots
  __shared__ u16 Vs[2][4096];       // 16384 B: [64 hd][64 keys], swizzled 16B slots
  __shared__ u16 Plds[4][16][64];   //  8192 B: [wave][q][key], XOR-swizzled, per-sub reuse
  const int t = threadIdx.x, lane = t & 63, w = t >> 6;
  const int fr = lane & 15, fq = lane >> 4;
  const int blk = blockIdx.x;
  const int qt = blk & 15;             // 16 q-tiles of 128 rows
  const int h  = (blk >> 4) & 31;
  const int b  = blk >> 9;
  const int kvh = h >> 2;
  const size_t rowb = (size_t)b * 2048;
  const u16* Qb  = QKV + rowb * 3072 + h * 64;
  const u16* Kb  = QKV + rowb * 3072 + 2048 + kvh * 64;
  const u16* VTb = VT + ((size_t)b * 512 + kvh * 64) * 2048;   // VT[hd][n]
  const int qrow0 = qt * 128 + w * 32;

  // Q fragments (pre-scaled by QK_SC2 via the wq tconv)
  bh8 qf[2][2];
#pragma unroll
  for (int sub = 0; sub < 2; sub++)
#pragma unroll
    for (int kk = 0; kk < 2; kk++)
      qf[sub][kk] = *(const bh8*)(Qb + (size_t)(qrow0 + sub * 16 + fr) * 3072 + kk * 32 + fq * 8);

  // all-ones bf16 B-fragment for the rowsum MFMA
  const bh8 ones8 = {0x3F80, 0x3F80, 0x3F80, 0x3F80, 0x3F80, 0x3F80, 0x3F80, 0x3F80};

  // Staging: chunk c covers tile row c>>3, 16B slot c&7; LDS dest linear;
  // global source uses inverse swizzle slot' = (c ^ (c>>3)) & 7.
  const int c0 = t, c1 = t + 256;
  const int r0 = c0 >> 3, s0 = (c0 ^ r0) & 7;
  const int r1 = c1 >> 3, s1 = (c1 ^ r1) & 7;
  const u16* ksrc0 = Kb  + (size_t)r0 * 3072 + s0 * 8;
  const u16* ksrc1 = Kb  + (size_t)r1 * 3072 + s1 * 8;
  const u16* vsrc0 = VTb + (size_t)r0 * 2048 + s0 * 8;
  const u16* vsrc1 = VTb + (size_t)r1 * 2048 + s1 * 8;

#define STAGE(buf, kb_) do {                                              \
    gload16(ksrc0 + (size_t)(kb_) * 64 * 3072, &Ks[buf][c0 * 8]);         \
    gload16(ksrc1 + (size_t)(kb_) * 64 * 3072, &Ks[buf][c1 * 8]);         \
    gload16(vsrc0 + (size_t)(kb_) * 64,        &Vs[buf][c0 * 8]);         \
    gload16(vsrc1 + (size_t)(kb_) * 64,        &Vs[buf][c1 * 8]);         \
  } while (0)

  STAGE(0, 0);
  asm volatile("s_waitcnt vmcnt(0)");
  __syncthreads();

  // swizzled read offset: tile row fr, global slot fq -> LDS slot fq^(fr&7)
  const unsigned rdOf = (unsigned)(fr * 128) + ((unsigned)(fq ^ (fr & 7)) << 4);
  // Plds row base (row = q = fr) and per-lane XOR swizzle
  char* Prow = (char*)&Plds[w][fr][0];
  const unsigned pswz = (unsigned)((fr & 7) << 4);

  f4 oacc[2][4] = {};
  f4 lacc[2] = {};

  for (int kb = 0; kb < 32; kb++) {
    const int cur = kb & 1;
    if (kb + 1 < 32) STAGE(cur ^ 1, kb + 1);

    const char* Kt  = (const char*)&Ks[cur][0];
    const char* Vtl = (const char*)&Vs[cur][0];

    // --- S^T = K Q^T (swapped operands): lane holds S[q=fr][key=c*16+fq*4+r],
    //     pre-scaled via Q ---
    f4 sf[2][4];
#pragma unroll
    for (int c = 0; c < 4; c++) {
      bh8 k0 = *(const bh8*)(Kt + c * 2048 + rdOf);
      bh8 k1 = *(const bh8*)(Kt + c * 2048 + (rdOf ^ 64));
      f4 s0v = {}, s1v = {};
      s0v = __builtin_amdgcn_mfma_f32_16x16x32_bf16(k0, qf[0][0], s0v, 0, 0, 0);
      s0v = __builtin_amdgcn_mfma_f32_16x16x32_bf16(k1, qf[0][1], s0v, 0, 0, 0);
      s1v = __builtin_amdgcn_mfma_f32_16x16x32_bf16(k0, qf[1][0], s1v, 0, 0, 0);
      s1v = __builtin_amdgcn_mfma_f32_16x16x32_bf16(k1, qf[1][1], s1v, 0, 0, 0);
      sf[0][c] = s0v; sf[1][c] = s1v;
    }

    // --- P = exp2(S): per sub, pack 4 keys -> 1 b64 swizzled write, then read
    //     the A-frags back. Buffer reused across subs: fence the WAR window
    //     (reads of sub-0 must RETURN before sub-1's writes issue). ---
    bh8 pa[2][2];
#pragma unroll
    for (int sub = 0; sub < 2; sub++) {
#pragma unroll
      for (int c = 0; c < 4; c++) {
        float p0 = exp2f(sf[sub][c][0]);
        float p1 = exp2f(sf[sub][c][1]);
        float p2 = exp2f(sf[sub][c][2]);
        float p3 = exp2f(sf[sub][c][3]);
        union { unsigned u[2]; unsigned long long ll; } pk;
        pk.u[0] = cvtpk_bf16(p0, p1);
        pk.u[1] = cvtpk_bf16(p2, p3);
        *(unsigned long long*)(Prow + (((unsigned)(c * 32 + fq * 8)) ^ pswz)) = pk.ll;
      }
      pa[sub][0] = *(const bh8*)(Prow + (((unsigned)(fq * 16)) ^ pswz));
      pa[sub][1] = *(const bh8*)(Prow + (((unsigned)(64 + fq * 16)) ^ pswz));
      asm volatile("s_waitcnt lgkmcnt(0)" ::: "memory");   // WAR fence: reads landed
    }

    // --- PV: O += P * V ; l += P * 1 (rowsum via ones-MFMA) ---
#pragma unroll
    for (int hc = 0; hc < 4; hc++) {
      bh8 v0 = *(const bh8*)(Vtl + hc * 2048 + rdOf);
      bh8 v1 = *(const bh8*)(Vtl + hc * 2048 + (rdOf ^ 64));
      oacc[0][hc] = __builtin_amdgcn_mfma_f32_16x16x32_bf16(pa[0][0], v0, oacc[0][hc], 0, 0, 0);
      oacc[0][hc] = __builtin_amdgcn_mfma_f32_16x16x32_bf16(pa[0][1], v1, oacc[0][hc], 0, 0, 0);
      oacc[1][hc] = __builtin_amdgcn_mfma_f32_16x16x32_bf16(pa[1][0], v0, oacc[1][hc], 0, 0, 0);
      oacc[1][hc] = __builtin_amdgcn_mfma_f32_16x16x32_bf16(pa[1][1], v1, oacc[1][hc], 0, 0, 0);
    }
    lacc[0] = __builtin_amdgcn_mfma_f32_16x16x32_bf16(pa[0][0], ones8, lacc[0], 0, 0, 0);
    lacc[0] = __builtin_amdgcn_mfma_f32_16x16x32_bf16(pa[0][1], ones8, lacc[0], 0, 0, 0);
    lacc[1] = __builtin_amdgcn_mfma_f32_16x16x32_bf16(pa[1][0], ones8, lacc[1], 0, 0, 0);
    lacc[1] = __builtin_amdgcn_mfma_f32_16x16x32_bf16(pa[1][1], ones8, lacc[1], 0, 0, 0);

    asm volatile("s_waitcnt vmcnt(0)");
    __syncthreads();
  }
#undef STAGE

  // --- epilogue: O / l ---
#pragma unroll
  for (int sub = 0; sub < 2; sub++)
#pragma unroll
    for (int r = 0; r < 4; r++) {
      float inv = 1.f / lacc[sub][r];
#pragma unroll
      for (int hc = 0; hc < 4; hc++) {
        float v = oacc[sub][hc][r] * inv;
        AO[(rowb + qrow0 + sub * 16 + fq * 4 + r) * 2048 + h * 64 + hc * 16 + fr] = f2bf(v);
      }
    }
}

extern "C" void kernel_launch(void* const* d_in, const int* in_sizes, int n_in,
                              void* d_out, int out_size, void* d_ws, size_t ws_size,
                              hipStream_t stream) {
  const float* x  = (const float*)d_in[0];
  const float* wq = (const float*)d_in[1];
  const float* wk = (const float*)d_in[2];
  const float* wv = (const float*)d_in[3];
  const float* wo = (const float*)d_in[4];
  float* out = (float*)d_out;
  char* ws = (char*)d_ws;
  u16* xb    = (u16*)(ws);                               // [4096][2048] bf16, 16 MB
  u16* AO    = (u16*)(ws);                               // [4096][2048] bf16 (reuse, xb dead)
  u16* wqkvT = (u16*)(ws + 16777216);                    // [3072][2048] bf16, 12 MB
  u16* VT    = (u16*)(ws + 16777216);                    // [2][512][2048] bf16, 4 MB (reuse, wqkvT dead)
  u16* woT   = (u16*)(ws + 16777216 + 12582912);         // [2048][2048] bf16, 8 MB
  u16* QKV   = (u16*)(ws + 37748736);                    // [4096][3072] bf16, 24 MB

  convx_kernel<<<4096, 256, 0, stream>>>(x, xb, 1048576);
  tconv4_kernel<<<dim3(160, 64), dim3(32, 8), 0, stream>>>(wq, wk, wv, wo, wqkvT, woT);

  gemm_bt<u16><<<dim3(24, 32), 256, 0, stream>>>(xb, wqkvT, QKV, 4096, 3072, 2048);
  vtrans_kernel<<<dim3(64, 16, 2), dim3(32, 8), 0, stream>>>(QKV, VT);   // wqkvT dead -> VT
  attn_kernel<<<1024, 256, 0, stream>>>(QKV, VT, AO);
  gemm_bt<float><<<dim3(16, 32), 256, 0, stream>>>(AO, woT, out, 4096, 2048, 2048);
}

// Round 19
// 246.632 us; speedup vs baseline: 1.1916x; 1.0093x over previous
//
#include <hip/hip_runtime.h>

typedef unsigned short u16;
typedef __attribute__((ext_vector_type(8))) short bh8;   // 8 bf16
typedef __attribute__((ext_vector_type(4))) float f4;

__device__ inline u16 f2bf(float f) {
  union { float f; unsigned u; } v; v.f = f;
  unsigned r = v.u + 0x7FFFu + ((v.u >> 16) & 1u);   // RNE
  return (u16)(r >> 16);
}

// softmax scale folded into wq at tconv: 0.125 * log2(e)
#define QK_SC2 0.18033688011112042f

// ------------- fused prep: x->bf16 convert + all 4 weight transposes (1 launch) -------------
// bid < 4096: convx (x fp32 -> xb bf16, 8 elems/thread).
// bid >= 4096: tconv, idx = bid-4096, by = idx&63, bx = idx>>6 in [0,160):
//   bx<64 wq(x QK_SC2) | <80 wk | <96 wv | else wo.  W[2048][N] fp32 -> Wt[N][2048] bf16.
__global__ __launch_bounds__(256) void prep_kernel(const float* __restrict__ x,
                                                   u16* __restrict__ xb,
                                                   const float* __restrict__ wq,
                                                   const float* __restrict__ wk,
                                                   const float* __restrict__ wv,
                                                   const float* __restrict__ wo,
                                                   u16* __restrict__ wqkvT,
                                                   u16* __restrict__ woT) {
  const int bid = blockIdx.x, t = threadIdx.x;
  if (bid < 4096) {
    int i = bid * 256 + t;                      // i < 1048576 always (4096*256)
    const float4* xf = (const float4*)x;
    float4 a = xf[2 * i], b = xf[2 * i + 1];
    alignas(16) u16 o[8] = { f2bf(a.x), f2bf(a.y), f2bf(a.z), f2bf(a.w),
                             f2bf(b.x), f2bf(b.y), f2bf(b.z), f2bf(b.w) };
    *(int4*)(xb + (size_t)i * 8) = *(const int4*)o;
    return;
  }
  const int idx = bid - 4096;
  const int by = idx & 63, bx = idx >> 6;
  const float* W; u16* Wt; int N; float scale; int nbx;
  if (bx < 64)      { W = wq; Wt = wqkvT;                       N = 2048; scale = QK_SC2; nbx = bx; }
  else if (bx < 80) { W = wk; Wt = wqkvT + (size_t)2048 * 2048; N = 512;  scale = 1.0f;  nbx = bx - 64; }
  else if (bx < 96) { W = wv; Wt = wqkvT + (size_t)2560 * 2048; N = 512;  scale = 1.0f;  nbx = bx - 80; }
  else              { W = wo; Wt = woT;                         N = 2048; scale = 1.0f;  nbx = bx - 96; }
  __shared__ float tile[32][33];
  int nb = nbx * 32, kb = by * 32;
  int tx = t & 31, ty = t >> 5;
  for (int i = ty; i < 32; i += 8)
    tile[i][tx] = W[(size_t)(kb + i) * N + nb + tx];
  __syncthreads();
  for (int i = ty; i < 32; i += 8)
    Wt[(size_t)(nb + i) * 2048 + kb + tx] = f2bf(tile[tx][i] * scale);
}

// ------------- V transpose: QKV V-cols [b][2048][512] -> VT[b][512][2048] bf16 -------------
__global__ __launch_bounds__(256) void vtrans_kernel(const u16* __restrict__ QKV,
                                                     u16* __restrict__ VT) {
  __shared__ u16 tile[32][33];
  int nb = blockIdx.x * 32, cb = blockIdx.y * 32, b = blockIdx.z;
  int tx = threadIdx.x, ty = threadIdx.y;
  for (int i = ty; i < 32; i += 8)
    tile[i][tx] = QKV[(size_t)(b * 2048 + nb + i) * 3072 + 2560 + cb + tx];
  __syncthreads();
  for (int i = ty; i < 32; i += 8)
    VT[((size_t)b * 512 + cb + i) * 2048 + nb + tx] = tile[tx][i];
}

// ---------------- async global->LDS 16B ----------------
__device__ inline void gload16(const u16* g, u16* l) {
  __builtin_amdgcn_global_load_lds(
      (const __attribute__((address_space(1))) unsigned int*)g,
      (__attribute__((address_space(3))) unsigned int*)l, 16, 0, 0);
}

__device__ inline unsigned cvtpk_bf16(float lo, float hi) {
  unsigned r;
  asm("v_cvt_pk_bf16_f32 %0, %1, %2" : "=v"(r) : "v"(lo), "v"(hi));
  return r;
}

// ---------------- GEMM: C[M][N] = A[M][K] * Bt[N][K]^T  (BK=64, verified r16) ----------------
template <typename OutT>
__global__ __launch_bounds__(256) void gemm_bt(const u16* __restrict__ A,
                                               const u16* __restrict__ Bt,
                                               OutT* __restrict__ C,
                                               int M, int N, int K) {
  __shared__ u16 As[128 * 64];   // 16 KB
  __shared__ u16 Bs[128 * 64];   // 16 KB
  const int t = threadIdx.x;
  const int lane = t & 63, w = t >> 6;
  const int wr = w >> 1, wc = w & 1;
  const int fr = lane & 15, fq = lane >> 4;
  const int rowBase = blockIdx.y * 128, colBase = blockIdx.x * 128;
  f4 acc[4][4] = {};
  const u16* Ag = A + (size_t)rowBase * K;
  const u16* Bg = Bt + (size_t)colBase * K;
  for (int kt = 0; kt < K; kt += 64) {
    __syncthreads();
#pragma unroll
    for (int i = 0; i < 4; i++) {
      int c = t + i * 256;
      int row = c >> 3, sl = (c ^ row) & 7;
      gload16(Ag + (size_t)row * K + kt + sl * 8, As + c * 8);
    }
#pragma unroll
    for (int i = 0; i < 4; i++) {
      int c = t + i * 256;
      int row = c >> 3, sl = (c ^ row) & 7;
      gload16(Bg + (size_t)row * K + kt + sl * 8, Bs + c * 8);
    }
    __syncthreads();
#pragma unroll
    for (int kk = 0; kk < 2; kk++) {
      bh8 a[4], b[4];
#pragma unroll
      for (int m = 0; m < 4; m++) {
        int row = wr * 64 + m * 16 + fr;
        int sl = (kk * 4 + fq) ^ (row & 7);
        a[m] = *(const bh8*)(As + row * 64 + sl * 8);
      }
#pragma unroll
      for (int n = 0; n < 4; n++) {
        int row = wc * 64 + n * 16 + fr;
        int sl = (kk * 4 + fq) ^ (row & 7);
        b[n] = *(const bh8*)(Bs + row * 64 + sl * 8);
      }
#pragma unroll
      for (int m = 0; m < 4; m++)
#pragma unroll
        for (int n = 0; n < 4; n++)
          acc[m][n] = __builtin_amdgcn_mfma_f32_16x16x32_bf16(a[m], b[n], acc[m][n], 0, 0, 0);
    }
  }
#pragma unroll
  for (int m = 0; m < 4; m++)
#pragma unroll
    for (int n = 0; n < 4; n++)
#pragma unroll
      for (int r = 0; r < 4; r++) {
        int row = rowBase + wr * 64 + m * 16 + fq * 4 + r;
        int col = colBase + wc * 64 + n * 16 + fr;
        float v = acc[m][n][r];
        if constexpr (sizeof(OutT) == 2)
          ((u16*)C)[(size_t)row * N + col] = f2bf(v);
        else
          ((float*)C)[(size_t)row * N + col] = v;
      }
}

// ---------------- fused flash attention (GQA, no mask) ----------------
// BYTE-IDENTICAL to the round-13/16/18 verified kernel -- the empirical optimum.
// QKV: [4096][3072] bf16; VT: [b][512][2048] bf16; AO: [4096][2048] bf16.
__global__ __launch_bounds__(256) void attn_kernel(const u16* __restrict__ QKV,
                                                   const u16* __restrict__ VT,
                                                   u16* __restrict__ AO) {
  __shared__ u16 Ks[2][4096];       // 16384 B: [64 keys][64 hd], swizzled 16B slots
  __shared__ u16 Vs[2][4096];       // 16384 B: [64 hd][64 keys], swizzled 16B slots
  __shared__ u16 Plds[4][16][64];   //  8192 B: [wave][q][key], XOR-swizzled, per-sub reuse
  const int t = threadIdx.x, lane = t & 63, w = t >> 6;
  const int fr = lane & 15, fq = lane >> 4;
  const int blk = blockIdx.x;
  const int qt = blk & 15;             // 16 q-tiles of 128 rows
  const int h  = (blk >> 4) & 31;
  const int b  = blk >> 9;
  const int kvh = h >> 2;
  const size_t rowb = (size_t)b * 2048;
  const u16* Qb  = QKV + rowb * 3072 + h * 64;
  const u16* Kb  = QKV + rowb * 3072 + 2048 + kvh * 64;
  const u16* VTb = VT + ((size_t)b * 512 + kvh * 64) * 2048;   // VT[hd][n]
  const int qrow0 = qt * 128 + w * 32;

  // Q fragments (pre-scaled by QK_SC2 via the wq tconv)
  bh8 qf[2][2];
#pragma unroll
  for (int sub = 0; sub < 2; sub++)
#pragma unroll
    for (int kk = 0; kk < 2; kk++)
      qf[sub][kk] = *(const bh8*)(Qb + (size_t)(qrow0 + sub * 16 + fr) * 3072 + kk * 32 + fq * 8);

  // all-ones bf16 B-fragment for the rowsum MFMA
  const bh8 ones8 = {0x3F80, 0x3F80, 0x3F80, 0x3F80, 0x3F80, 0x3F80, 0x3F80, 0x3F80};

  // Staging: chunk c covers tile row c>>3, 16B slot c&7; LDS dest linear;
  // global source uses inverse swizzle slot' = (c ^ (c>>3)) & 7.
  const int c0 = t, c1 = t + 256;
  const int r0 = c0 >> 3, s0 = (c0 ^ r0) & 7;
  const int r1 = c1 >> 3, s1 = (c1 ^ r1) & 7;
  const u16* ksrc0 = Kb  + (size_t)r0 * 3072 + s0 * 8;
  const u16* ksrc1 = Kb  + (size_t)r1 * 3072 + s1 * 8;
  const u16* vsrc0 = VTb + (size_t)r0 * 2048 + s0 * 8;
  const u16* vsrc1 = VTb + (size_t)r1 * 2048 + s1 * 8;

#define STAGE(buf, kb_) do {                                              \
    gload16(ksrc0 + (size_t)(kb_) * 64 * 3072, &Ks[buf][c0 * 8]);         \
    gload16(ksrc1 + (size_t)(kb_) * 64 * 3072, &Ks[buf][c1 * 8]);         \
    gload16(vsrc0 + (size_t)(kb_) * 64,        &Vs[buf][c0 * 8]);         \
    gload16(vsrc1 + (size_t)(kb_) * 64,        &Vs[buf][c1 * 8]);         \
  } while (0)

  STAGE(0, 0);
  asm volatile("s_waitcnt vmcnt(0)");
  __syncthreads();

  // swizzled read offset: tile row fr, global slot fq -> LDS slot fq^(fr&7)
  const unsigned rdOf = (unsigned)(fr * 128) + ((unsigned)(fq ^ (fr & 7)) << 4);
  // Plds row base (row = q = fr) and per-lane XOR swizzle
  char* Prow = (char*)&Plds[w][fr][0];
  const unsigned pswz = (unsigned)((fr & 7) << 4);

  f4 oacc[2][4] = {};
  f4 lacc[2] = {};

  for (int kb = 0; kb < 32; kb++) {
    const int cur = kb & 1;
    if (kb + 1 < 32) STAGE(cur ^ 1, kb + 1);

    const char* Kt  = (const char*)&Ks[cur][0];
    const char* Vtl = (const char*)&Vs[cur][0];

    // --- S^T = K Q^T (swapped operands): lane holds S[q=fr][key=c*16+fq*4+r],
    //     pre-scaled via Q ---
    f4 sf[2][4];
#pragma unroll
    for (int c = 0; c < 4; c++) {
      bh8 k0 = *(const bh8*)(Kt + c * 2048 + rdOf);
      bh8 k1 = *(const bh8*)(Kt + c * 2048 + (rdOf ^ 64));
      f4 s0v = {}, s1v = {};
      s0v = __builtin_amdgcn_mfma_f32_16x16x32_bf16(k0, qf[0][0], s0v, 0, 0, 0);
      s0v = __builtin_amdgcn_mfma_f32_16x16x32_bf16(k1, qf[0][1], s0v, 0, 0, 0);
      s1v = __builtin_amdgcn_mfma_f32_16x16x32_bf16(k0, qf[1][0], s1v, 0, 0, 0);
      s1v = __builtin_amdgcn_mfma_f32_16x16x32_bf16(k1, qf[1][1], s1v, 0, 0, 0);
      sf[0][c] = s0v; sf[1][c] = s1v;
    }

    // --- P = exp2(S): per sub, pack 4 keys -> 1 b64 swizzled write, then read
    //     the A-frags back. Buffer reused across subs: fence the WAR window
    //     (reads of sub-0 must RETURN before sub-1's writes issue). ---
    bh8 pa[2][2];
#pragma unroll
    for (int sub = 0; sub < 2; sub++) {
#pragma unroll
      for (int c = 0; c < 4; c++) {
        float p0 = exp2f(sf[sub][c][0]);
        float p1 = exp2f(sf[sub][c][1]);
        float p2 = exp2f(sf[sub][c][2]);
        float p3 = exp2f(sf[sub][c][3]);
        union { unsigned u[2]; unsigned long long ll; } pk;
        pk.u[0] = cvtpk_bf16(p0, p1);
        pk.u[1] = cvtpk_bf16(p2, p3);
        *(unsigned long long*)(Prow + (((unsigned)(c * 32 + fq * 8)) ^ pswz)) = pk.ll;
      }
      pa[sub][0] = *(const bh8*)(Prow + (((unsigned)(fq * 16)) ^ pswz));
      pa[sub][1] = *(const bh8*)(Prow + (((unsigned)(64 + fq * 16)) ^ pswz));
      asm volatile("s_waitcnt lgkmcnt(0)" ::: "memory");   // WAR fence: reads landed
    }

    // --- PV: O += P * V ; l += P * 1 (rowsum via ones-MFMA) ---
#pragma unroll
    for (int hc = 0; hc < 4; hc++) {
      bh8 v0 = *(const bh8*)(Vtl + hc * 2048 + rdOf);
      bh8 v1 = *(const bh8*)(Vtl + hc * 2048 + (rdOf ^ 64));
      oacc[0][hc] = __builtin_amdgcn_mfma_f32_16x16x32_bf16(pa[0][0], v0, oacc[0][hc], 0, 0, 0);
      oacc[0][hc] = __builtin_amdgcn_mfma_f32_16x16x32_bf16(pa[0][1], v1, oacc[0][hc], 0, 0, 0);
      oacc[1][hc] = __builtin_amdgcn_mfma_f32_16x16x32_bf16(pa[1][0], v0, oacc[1][hc], 0, 0, 0);
      oacc[1][hc] = __builtin_amdgcn_mfma_f32_16x16x32_bf16(pa[1][1], v1, oacc[1][hc], 0, 0, 0);
    }
    lacc[0] = __builtin_amdgcn_mfma_f32_16x16x32_bf16(pa[0][0], ones8, lacc[0], 0, 0, 0);
    lacc[0] = __builtin_amdgcn_mfma_f32_16x16x32_bf16(pa[0][1], ones8, lacc[0], 0, 0, 0);
    lacc[1] = __builtin_amdgcn_mfma_f32_16x16x32_bf16(pa[1][0], ones8, lacc[1], 0, 0, 0);
    lacc[1] = __builtin_amdgcn_mfma_f32_16x16x32_bf16(pa[1][1], ones8, lacc[1], 0, 0, 0);

    asm volatile("s_waitcnt vmcnt(0)");
    __syncthreads();
  }
#undef STAGE

  // --- epilogue: O / l ---
#pragma unroll
  for (int sub = 0; sub < 2; sub++)
#pragma unroll
    for (int r = 0; r < 4; r++) {
      float inv = 1.f / lacc[sub][r];
#pragma unroll
      for (int hc = 0; hc < 4; hc++) {
        float v = oacc[sub][hc][r] * inv;
        AO[(rowb + qrow0 + sub * 16 + fq * 4 + r) * 2048 + h * 64 + hc * 16 + fr] = f2bf(v);
      }
    }
}

extern "C" void kernel_launch(void* const* d_in, const int* in_sizes, int n_in,
                              void* d_out, int out_size, void* d_ws, size_t ws_size,
                              hipStream_t stream) {
  const float* x  = (const float*)d_in[0];
  const float* wq = (const float*)d_in[1];
  const float* wk = (const float*)d_in[2];
  const float* wv = (const float*)d_in[3];
  const float* wo = (const float*)d_in[4];
  float* out = (float*)d_out;
  char* ws = (char*)d_ws;
  u16* xb    = (u16*)(ws);                               // [4096][2048] bf16, 16 MB
  u16* AO    = (u16*)(ws);                               // [4096][2048] bf16 (reuse, xb dead)
  u16* wqkvT = (u16*)(ws + 16777216);                    // [3072][2048] bf16, 12 MB
  u16* VT    = (u16*)(ws + 16777216);                    // [2][512][2048] bf16, 4 MB (reuse, wqkvT dead)
  u16* woT   = (u16*)(ws + 16777216 + 12582912);         // [2048][2048] bf16, 8 MB
  u16* QKV   = (u16*)(ws + 37748736);                    // [4096][3072] bf16, 24 MB

  prep_kernel<<<4096 + 160 * 64, 256, 0, stream>>>(x, xb, wq, wk, wv, wo, wqkvT, woT);

  gemm_bt<u16><<<dim3(24, 32), 256, 0, stream>>>(xb, wqkvT, QKV, 4096, 3072, 2048);
  vtrans_kernel<<<dim3(64, 16, 2), dim3(32, 8), 0, stream>>>(QKV, VT);   // wqkvT dead -> VT
  attn_kernel<<<1024, 256, 0, stream>>>(QKV, VT, AO);
  gemm_bt<float><<<dim3(16, 32), 256, 0, stream>>>(AO, woT, out, 4096, 2048, 2048);
}